// Round 14
// baseline (75.325 us; speedup 1.0000x reference)
//
#include <hip/hip_runtime.h>

#define D_M     64
#define L_OBS   256
#define ALPHA   256
#define D_H     256
#define D_V     64
#define N_HEADS 8

typedef _Float16 half8 __attribute__((ext_vector_type(8)));
typedef float    f32x4 __attribute__((ext_vector_type(4)));

// ---------------------------------------------------------------------------
// Kernel 1: prep. Blocks 0..63: per-row imputation (wave-scan cummax).
// Blocks 64..191: per-(h, 16-a-chunk) fold: Qa = theta_a.wq^T + wq_b,
// QW[d][a] = Qa.wk[.][d]; also QWabs[a] = sum_{d>=1} |QW[d][a]| (softmax bound).
// ---------------------------------------------------------------------------
__global__ __launch_bounds__(256) void prep_kernel(
    const float* __restrict__ x_ts, const float* __restrict__ t_ts,
    const float* __restrict__ gm,
    const float* __restrict__ t2v_w, const float* __restrict__ t2v_phi,
    const float* __restrict__ wq_w, const float* __restrict__ wq_b,
    const float* __restrict__ wk_w,
    float* __restrict__ regular, float* __restrict__ QWbuf,
    float* __restrict__ QWabsG)
{
    const int tid = threadIdx.x;

    __shared__ int   last[ALPHA];
    __shared__ float vals[ALPHA];
    __shared__ int   wtot[4];
    __shared__ __align__(16) float wq_s[D_V][68];
    __shared__ __align__(16) float thA[16][68];
    __shared__ __align__(16) float QaT[16][68];

    if (blockIdx.x < D_M) {
        // ---------------- imputation ----------------
        const int m  = blockIdx.x;
        const int l  = tid;
        const int wv = tid >> 6;
        const int ln = tid & 63;
        last[l] = -1;
        __syncthreads();
        float x = x_ts[m * L_OBS + l];
        float t = t_ts[m * L_OBS + l];
        bool valid = (x == x) && (t >= 0.0f);
        int idx = (int)t;
        if (valid && idx < ALPHA) atomicMax(&last[idx], l);
        __syncthreads();
        int li = last[l];
        vals[l] = (li >= 0) ? x_ts[m * L_OBS + li] : 0.0f;
        int p = (li >= 0) ? l : -1;
        #pragma unroll
        for (int s = 1; s < 64; s <<= 1) {
            int q = __shfl_up(p, s);
            if (ln >= s && q > p) p = q;
        }
        if (ln == 63) wtot[wv] = p;
        __syncthreads();
        int pre = -1;
        for (int w = 0; w < 4; w++)
            if (w < wv && wtot[w] > pre) pre = wtot[w];
        int lp = (pre > p) ? pre : p;
        regular[m * ALPHA + l] = (lp >= 0) ? vals[lp] : gm[m];
    } else {
        // ---------------- weight fold + QW for 16 a ----------------
        const int pb = blockIdx.x - D_M;   // 0..127
        const int h  = pb >> 4;
        const int a0 = (pb & 15) * 16;

        {
            const float4* w4 = (const float4*)(wq_w + h * D_V * D_V);
            #pragma unroll
            for (int i = 0; i < 4; i++) {
                int f = i * 256 + tid;
                float4 v = w4[f];
                int e = f >> 4, c = (f & 15) * 4;
                *(float4*)&wq_s[e][c] = v;
            }
        }
        {
            int al = tid >> 4, j0 = (tid & 15) * 4;
            float tv = (float)(a0 + al);
            #pragma unroll
            for (int j = 0; j < 4; j++) {
                int d = j0 + j;
                float f = t2v_w[h * D_V + d] * tv + t2v_phi[h * D_V + d];
                thA[al][d] = (d == 0) ? f : __sinf(f);
            }
        }
        __syncthreads();

        // Phase A: QaT[a][e] = thA[a] . wq_s[e] + wq_b[e]
        {
            const int e  = tid >> 2;
            const int ap = tid & 3;
            float accA[4] = {0.f, 0.f, 0.f, 0.f};
            const float4* wrow = (const float4*)&wq_s[e][0];
            #pragma unroll
            for (int j = 0; j < 16; j++) {
                float4 w = wrow[j];
                #pragma unroll
                for (int k = 0; k < 4; k++) {
                    float4 tv = *(const float4*)&thA[ap + 4 * k][j * 4];
                    accA[k] += w.x * tv.x + w.y * tv.y + w.z * tv.z + w.w * tv.w;
                }
            }
            float bq = wq_b[h * D_V + e];
            #pragma unroll
            for (int k = 0; k < 4; k++) QaT[ap + 4 * k][e] = accA[k] + bq;
        }
        __syncthreads();

        // Phase B: QW[d][a] = sum_e QaT[a][e] * wk_w[h][e][d]
        const int d  = tid >> 2;
        const int ap = tid & 3;
        float accB[4] = {0.f, 0.f, 0.f, 0.f};
        #pragma unroll 4
        for (int e4 = 0; e4 < 16; e4++) {
            const float* wkp = &wk_w[(h * D_V + e4 * 4) * D_V + d];
            float w0 = wkp[0];
            float w1 = wkp[D_V];
            float w2 = wkp[2 * D_V];
            float w3 = wkp[3 * D_V];
            #pragma unroll
            for (int k = 0; k < 4; k++) {
                float4 qv = *(const float4*)&QaT[ap + 4 * k][e4 * 4];
                accB[k] += qv.x * w0 + qv.y * w1 + qv.z * w2 + qv.w * w3;
            }
        }
        #pragma unroll
        for (int k = 0; k < 4; k++)
            QWbuf[h * D_V * ALPHA + d * ALPHA + a0 + ap + 4 * k] = accB[k];

        // QWabs reduction: wq_s reused as red[d][a-local]
        __syncthreads();
        #pragma unroll
        for (int k = 0; k < 4; k++)
            wq_s[d][ap + 4 * k] = (d == 0) ? 0.0f : fabsf(accB[k]);
        __syncthreads();
        if (tid < 16) {
            float s = 0.0f;
            #pragma unroll 8
            for (int dd = 0; dd < D_V; dd++) s += wq_s[dd][tid];
            QWabsG[h * ALPHA + a0 + tid] = s;
        }
    }
}

// ---------------------------------------------------------------------------
// Kernel 2: mTAND attention via MFMA, SPLIT over l into 2 half-blocks for
// occupancy (grid (2,64,8) = 1024 blocks = 4 waves/SIMD). Each block handles
// 8 of the 16 l-tiles and emits PARTIAL (A,S) sums -- exact under the
// bound-shifted softmax (no max state; the bound sB is identical in both
// halves since it derives from the whole row's valid-t extremes).
// Double-buffered sin-fragment LDS (one barrier per tile, writer VALU
// overlaps reader MFMA); d=0 linear term exact in fp32 as C-init; d>=1 via
// 3-term split-precision f16 MFMA (same d-slot formula on A and B).
// ---------------------------------------------------------------------------
__global__ __launch_bounds__(256) void attn_mfma_kernel(
    const float* __restrict__ x_ts, const float* __restrict__ t_ts,
    const float* __restrict__ t2v_w, const float* __restrict__ t2v_phi,
    const float* __restrict__ QWbuf, const float* __restrict__ QWabsG,
    float* __restrict__ pA, float* __restrict__ pS)
{
    const int lh  = blockIdx.x;          // l-half (8 tiles each)
    const int m   = blockIdx.y;
    const int h   = blockIdx.z;
    const int tid = threadIdx.x;
    const int wv  = tid >> 6;
    const int ln  = tid & 63;
    const int lg  = ln >> 4;             // lane group (0..3)
    const int lc  = ln & 15;             // B col / A row within tile

    __shared__ float t_sh[L_OBS], x_sh[L_OBS], mk_sh[L_OBS];
    __shared__ float w_sh[D_V], phi_sh[D_V];
    __shared__ __align__(16) _Float16 hiB[2048];   // 4 KiB, 2 buffers
    __shared__ __align__(16) _Float16 reB[2048];   // 4 KiB, 2 buffers
    __shared__ float red_s[8];

    {
        float x = x_ts[m * L_OBS + tid];
        float t = t_ts[m * L_OBS + tid];
        bool v = (x == x) && (t >= 0.0f);
        x_sh[tid]  = v ? x : 0.0f;
        t_sh[tid]  = v ? t : 0.0f;
        mk_sh[tid] = v ? 0.0f : -1.0e9f;
        float tmx = v ? t : -3.0e38f;
        float tmn = v ? t : 3.0e38f;
        #pragma unroll
        for (int s = 1; s < 64; s <<= 1) {
            tmx = fmaxf(tmx, __shfl_xor(tmx, s));
            tmn = fminf(tmn, __shfl_xor(tmn, s));
        }
        if (ln == 0) { red_s[wv] = tmx; red_s[4 + wv] = tmn; }
    }
    if (tid < D_V)          w_sh[tid]         = t2v_w[h * D_V + tid];
    else if (tid < 2 * D_V) phi_sh[tid - D_V] = t2v_phi[h * D_V + tid - D_V];
    __syncthreads();

    const float tmaxv = fmaxf(fmaxf(red_s[0], red_s[1]), fmaxf(red_s[2], red_s[3]));
    const float tminv = fminf(fminf(red_s[4], red_s[5]), fminf(red_s[6], red_s[7]));

    const float* __restrict__ QWh = QWbuf + h * D_V * ALPHA;
    const float w0 = w_sh[0], p0 = phi_sh[0];
    const float SCALE2 = 0.18033688011112042f;   // 0.125 * log2(e)

    // ---- stage A fragments (hi + residual) + bound-folded C-init ----
    half8 ahf[4][2], arf[4][2];
    float qw0[4][4], c0b[4][4];
    #pragma unroll
    for (int at = 0; at < 4; at++) {
        const int abase = wv * 64 + at * 16;
        const int arowA = abase + lc;
        #pragma unroll
        for (int kb = 0; kb < 2; kb++) {
            #pragma unroll
            for (int j = 0; j < 8; j++) {
                int d = 1 + kb * 32 + ((j >> 2) << 4) + (lg << 2) + (j & 3);
                float q = (d < D_V) ? QWh[d * ALPHA + arowA] : 0.0f;
                _Float16 qh = (_Float16)q;
                ahf[at][kb][j] = qh;
                arf[at][kb][j] = (_Float16)(q - (float)qh);
            }
        }
        const int arowD = abase + lg * 4;
        #pragma unroll
        for (int r = 0; r < 4; r++) {
            float q0 = QWh[arowD + r];
            qw0[at][r] = q0;
            float u = q0 * w0;
            float lin = q0 * p0 + fmaxf(u * tmaxv, u * tminv);
            c0b[at][r] = -(lin + QWabsG[h * ALPHA + arowD + r]);
        }
    }

    float ssum[4][4], axs[4][4];
    #pragma unroll
    for (int at = 0; at < 4; at++)
        #pragma unroll
        for (int r = 0; r < 4; r++) { ssum[at][r] = 0.0f; axs[at][r] = 0.0f; }

    // writer-role constants
    const int wc  = tid >> 5;                 // combo = kb*4+lg, 0..7
    const int lcw = (tid >> 1) & 15;          // l within tile
    const int dB  = 1 + (wc >> 2) * 32 + (wc & 3) * 4 + ((tid & 1) << 4);

    auto write_frags = [&](int lt, int buf) {
        float tvw = t_sh[lt * 16 + lcw];
        float s0 = __sinf(fmaf(w_sh[(dB + 0) & 63], tvw, phi_sh[(dB + 0) & 63]));
        float s1 = __sinf(fmaf(w_sh[(dB + 1) & 63], tvw, phi_sh[(dB + 1) & 63]));
        float s2 = __sinf(fmaf(w_sh[(dB + 2) & 63], tvw, phi_sh[(dB + 2) & 63]));
        float s3 = __sinf(fmaf(w_sh[(dB + 3) & 63], tvw, phi_sh[(dB + 3) & 63]));
        union { _Float16 hv[4]; float2 f2; } hw, rw;
        hw.hv[0] = (_Float16)s0; hw.hv[1] = (_Float16)s1;
        hw.hv[2] = (_Float16)s2; hw.hv[3] = (_Float16)s3;
        rw.hv[0] = (_Float16)(s0 - (float)hw.hv[0]);
        rw.hv[1] = (_Float16)(s1 - (float)hw.hv[1]);
        rw.hv[2] = (_Float16)(s2 - (float)hw.hv[2]);
        rw.hv[3] = (_Float16)(s3 - (float)hw.hv[3]);
        *(float2*)&hiB[buf * 1024 + tid * 4] = hw.f2;
        *(float2*)&reB[buf * 1024 + tid * 4] = rw.f2;
    };

    // prologue: this half's first tile into buffer 0
    write_frags(lh * 8, 0);
    __syncthreads();

    // ---- main loop over this half's 8 l-tiles, one barrier each ----
    for (int i = 0; i < 8; i++) {
        const int lt  = lh * 8 + i;
        const int cur = i & 1;
        half8 bh[2], br[2];
        #pragma unroll
        for (int kb = 0; kb < 2; kb++) {
            int fi = cur * 1024 + ((kb * 4 + lg) * 16 + lc) * 8;
            bh[kb] = *(const half8*)&hiB[fi];
            br[kb] = *(const half8*)&reB[fi];
        }
        if (i < 7) write_frags(lt + 1, cur ^ 1);

        const int l = lt * 16 + lc;
        const float tv  = t_sh[l];
        const float xv  = x_sh[l];
        const float mkv = mk_sh[l];
        const float tau = fmaf(w0, tv, p0);

        #pragma unroll
        for (int at = 0; at < 4; at++) {
            f32x4 acc;
            #pragma unroll
            for (int r = 0; r < 4; r++)
                acc[r] = fmaf(qw0[at][r], tau, c0b[at][r]);  // exact d=0 - bound
            #pragma unroll
            for (int kb = 0; kb < 2; kb++) {
                acc = __builtin_amdgcn_mfma_f32_16x16x32_f16(ahf[at][kb], bh[kb], acc, 0, 0, 0);
                acc = __builtin_amdgcn_mfma_f32_16x16x32_f16(ahf[at][kb], br[kb], acc, 0, 0, 0);
                acc = __builtin_amdgcn_mfma_f32_16x16x32_f16(arf[at][kb], bh[kb], acc, 0, 0, 0);
            }
            #pragma unroll
            for (int r = 0; r < 4; r++) {
                float p = __builtin_amdgcn_exp2f(fmaf(acc[r], SCALE2, mkv));
                ssum[at][r] += p;
                axs[at][r]   = fmaf(p, xv, axs[at][r]);
            }
        }
        __syncthreads();
    }

    // ---- merge across the 16 lc lanes, write PARTIAL A,S [lh][a][m][h] ----
    #pragma unroll
    for (int at = 0; at < 4; at++) {
        #pragma unroll
        for (int r = 0; r < 4; r++) {
            float S = ssum[at][r];
            float A = axs[at][r];
            S += __shfl_xor(S, 1); A += __shfl_xor(A, 1);
            S += __shfl_xor(S, 2); A += __shfl_xor(A, 2);
            S += __shfl_xor(S, 4); A += __shfl_xor(A, 4);
            S += __shfl_xor(S, 8); A += __shfl_xor(A, 8);
            if (lc == 0) {
                int a = wv * 64 + at * 16 + lg * 4 + r;
                int idx = lh * (ALPHA * D_M * N_HEADS)
                        + a * (D_M * N_HEADS) + m * N_HEADS + h;
                pA[idx] = A;
                pS[idx] = S;
            }
        }
    }
}

// ---------------------------------------------------------------------------
// Kernel 3: fused e_imp + e_attn + gate MLP + output. Block per a (grid 256,
// the proven-parallel config). Combines the two attention partials:
// interp = (A0+A1)/(S0+S1), guarded to 0 when S==0 (fully-invalid feature).
// ---------------------------------------------------------------------------
__global__ __launch_bounds__(256) void final_kernel(
    const float* __restrict__ regular,
    const float* __restrict__ pA, const float* __restrict__ pS,
    const float* __restrict__ conv_w, const float* __restrict__ conv_b,
    const float* __restrict__ proj_w, const float* __restrict__ proj_b,
    const float* __restrict__ g1_w, const float* __restrict__ g1_b,
    const float* __restrict__ g2_w, const float* __restrict__ g2_b,
    float* __restrict__ out)
{
    const int a = blockIdx.x;
    const int tid = threadIdx.x;
    const int HALF = ALPHA * D_M * N_HEADS;
    __shared__ float isum_s[N_HEADS];
    __shared__ __align__(16) float col[D_M];
    __shared__ __align__(16) float c_s[2 * D_H];
    __shared__ __align__(16) float h_s[D_H];

    if (tid < 64) {
        int base = a * (D_M * N_HEADS) + tid * 8;
        const float4* a04 = (const float4*)&pA[base];
        const float4* a14 = (const float4*)&pA[HALF + base];
        const float4* s04 = (const float4*)&pS[base];
        const float4* s14 = (const float4*)&pS[HALF + base];
        float4 A0 = a04[0], A1 = a04[1], B0 = a14[0], B1 = a14[1];
        float4 S0 = s04[0], S1 = s04[1], T0 = s14[0], T1 = s14[1];
        float Av[8] = {A0.x + B0.x, A0.y + B0.y, A0.z + B0.z, A0.w + B0.w,
                       A1.x + B1.x, A1.y + B1.y, A1.z + B1.z, A1.w + B1.w};
        float Sv[8] = {S0.x + T0.x, S0.y + T0.y, S0.z + T0.z, S0.w + T0.w,
                       S1.x + T1.x, S1.y + T1.y, S1.z + T1.z, S1.w + T1.w};
        float v[8];
        #pragma unroll
        for (int j = 0; j < 8; j++) v[j] = (Sv[j] > 0.0f) ? (Av[j] / Sv[j]) : 0.0f;
        #pragma unroll
        for (int s = 1; s < 64; s <<= 1) {
            #pragma unroll
            for (int j = 0; j < 8; j++) v[j] += __shfl_xor(v[j], s);
        }
        if (tid == 0) {
            #pragma unroll
            for (int j = 0; j < 8; j++) isum_s[j] = v[j];
        }
    } else if (tid < 128) {
        col[tid - 64] = regular[(tid - 64) * ALPHA + a];
    }
    __syncthreads();

    float vattn;
    {
        const float4* p4 = (const float4*)&proj_w[tid * N_HEADS];
        float4 v0 = p4[0], v1 = p4[1];
        float sum = v0.x * isum_s[0] + v0.y * isum_s[1] + v0.z * isum_s[2]
                  + v0.w * isum_s[3] + v1.x * isum_s[4] + v1.y * isum_s[5]
                  + v1.z * isum_s[6] + v1.w * isum_s[7];
        vattn = proj_b[tid] + sum * (1.0f / 64.0f);
    }
    float vimp;
    {
        const float4* row = (const float4*)&conv_w[tid * D_M];
        const float4* c4  = (const float4*)col;
        float s0 = 0.f, s1 = 0.f, s2 = 0.f, s3 = 0.f;
        #pragma unroll
        for (int i = 0; i < D_M / 4; i++) {
            float4 r = row[i]; float4 c = c4[i];
            s0 += r.x * c.x; s1 += r.y * c.y; s2 += r.z * c.z; s3 += r.w * c.w;
        }
        vimp = conv_b[tid] + ((s0 + s1) + (s2 + s3));
    }
    c_s[tid]       = vimp;
    c_s[D_H + tid] = vattn;
    __syncthreads();

    {
        const float4* grow = (const float4*)&g1_w[tid * 2 * D_H];
        const float4* c4 = (const float4*)c_s;
        float s0 = 0.f, s1 = 0.f, s2 = 0.f, s3 = 0.f;
        #pragma unroll 8
        for (int i = 0; i < (2 * D_H) / 4; i++) {
            float4 g = grow[i]; float4 c = c4[i];
            s0 += g.x * c.x; s1 += g.y * c.y; s2 += g.z * c.z; s3 += g.w * c.w;
        }
        float hid = g1_b[tid] + ((s0 + s1) + (s2 + s3));
        h_s[tid] = fmaxf(hid, 0.0f);
    }
    __syncthreads();
    {
        const float4* grow = (const float4*)&g2_w[tid * D_H];
        const float4* h4 = (const float4*)h_s;
        float s0 = 0.f, s1 = 0.f, s2 = 0.f, s3 = 0.f;
        #pragma unroll 8
        for (int i = 0; i < D_H / 4; i++) {
            float4 g = grow[i]; float4 hh = h4[i];
            s0 += g.x * hh.x; s1 += g.y * hh.y; s2 += g.z * hh.z; s3 += g.w * hh.w;
        }
        float z = g2_b[tid] + ((s0 + s1) + (s2 + s3));
        float gate = 1.0f / (1.0f + __expf(-z));
        out[a * D_H + tid] = gate * vimp + (1.0f - gate) * vattn;
    }
}

// ---------------------------------------------------------------------------
extern "C" void kernel_launch(void* const* d_in, const int* in_sizes, int n_in,
                              void* d_out, int out_size, void* d_ws, size_t ws_size,
                              hipStream_t stream)
{
    (void)in_sizes; (void)n_in; (void)out_size; (void)ws_size;

    const float* x_ts    = (const float*)d_in[0];
    const float* t_ts    = (const float*)d_in[1];
    const float* gm      = (const float*)d_in[2];
    const float* conv_w  = (const float*)d_in[3];
    const float* conv_b  = (const float*)d_in[4];
    const float* t2v_w   = (const float*)d_in[5];
    const float* t2v_phi = (const float*)d_in[6];
    const float* wq_w    = (const float*)d_in[7];
    const float* wq_b    = (const float*)d_in[8];
    const float* wk_w    = (const float*)d_in[9];
    const float* proj_w  = (const float*)d_in[11];
    const float* proj_b  = (const float*)d_in[12];
    const float* g1_w    = (const float*)d_in[13];
    const float* g1_b    = (const float*)d_in[14];
    const float* g2_w    = (const float*)d_in[15];
    const float* g2_b    = (const float*)d_in[16];

    float* out = (float*)d_out;

    float* ws      = (float*)d_ws;
    float* regular = ws;                               // 16384
    float* QWbuf   = regular + D_M * ALPHA;            // 131072  [h][d][a]
    float* pA      = QWbuf + N_HEADS * D_V * ALPHA;    // 262144  [lh][a][m][h]
    float* pS      = pA + 2 * ALPHA * D_M * N_HEADS;   // 262144  [lh][a][m][h]
    float* QWabs   = pS + 2 * ALPHA * D_M * N_HEADS;   // 2048    [h][a]

    prep_kernel<<<D_M + 128, 256, 0, stream>>>(
        x_ts, t_ts, gm, t2v_w, t2v_phi, wq_w, wq_b, wk_w,
        regular, QWbuf, QWabs);
    attn_mfma_kernel<<<dim3(2, D_M, N_HEADS), 256, 0, stream>>>(
        x_ts, t_ts, t2v_w, t2v_phi, QWbuf, QWabs, pA, pS);
    final_kernel<<<ALPHA, 256, 0, stream>>>(
        regular, pA, pS, conv_w, conv_b, proj_w, proj_b,
        g1_w, g1_b, g2_w, g2_b, out);
}

// Round 15
// 57.589 us; speedup vs baseline: 1.3080x; 1.3080x over previous
//
#include <hip/hip_runtime.h>

#define D_M     64
#define L_OBS   256
#define ALPHA   256
#define D_H     256
#define D_V     64
#define N_HEADS 8

typedef _Float16 half8 __attribute__((ext_vector_type(8)));
typedef float    f32x4 __attribute__((ext_vector_type(4)));

// ---------------------------------------------------------------------------
// Kernel 1: prep. Blocks 0..63: per-row imputation (wave-scan cummax).
// Blocks 64..191: per-(h, 16-a-chunk) fold: Qa = theta_a.wq^T + wq_b,
// QW[d][a] = Qa.wk[.][d]; also QWabs[a] = sum_{d>=1} |QW[d][a]| (softmax bound).
// ---------------------------------------------------------------------------
__global__ __launch_bounds__(256) void prep_kernel(
    const float* __restrict__ x_ts, const float* __restrict__ t_ts,
    const float* __restrict__ gm,
    const float* __restrict__ t2v_w, const float* __restrict__ t2v_phi,
    const float* __restrict__ wq_w, const float* __restrict__ wq_b,
    const float* __restrict__ wk_w,
    float* __restrict__ regular, float* __restrict__ QWbuf,
    float* __restrict__ QWabsG)
{
    const int tid = threadIdx.x;

    __shared__ int   last[ALPHA];
    __shared__ float vals[ALPHA];
    __shared__ int   wtot[4];
    __shared__ __align__(16) float wq_s[D_V][68];
    __shared__ __align__(16) float thA[16][68];
    __shared__ __align__(16) float QaT[16][68];

    if (blockIdx.x < D_M) {
        // ---------------- imputation ----------------
        const int m  = blockIdx.x;
        const int l  = tid;
        const int wv = tid >> 6;
        const int ln = tid & 63;
        last[l] = -1;
        __syncthreads();
        float x = x_ts[m * L_OBS + l];
        float t = t_ts[m * L_OBS + l];
        bool valid = (x == x) && (t >= 0.0f);
        int idx = (int)t;
        if (valid && idx < ALPHA) atomicMax(&last[idx], l);
        __syncthreads();
        int li = last[l];
        vals[l] = (li >= 0) ? x_ts[m * L_OBS + li] : 0.0f;
        int p = (li >= 0) ? l : -1;
        #pragma unroll
        for (int s = 1; s < 64; s <<= 1) {
            int q = __shfl_up(p, s);
            if (ln >= s && q > p) p = q;
        }
        if (ln == 63) wtot[wv] = p;
        __syncthreads();
        int pre = -1;
        for (int w = 0; w < 4; w++)
            if (w < wv && wtot[w] > pre) pre = wtot[w];
        int lp = (pre > p) ? pre : p;
        regular[m * ALPHA + l] = (lp >= 0) ? vals[lp] : gm[m];
    } else {
        // ---------------- weight fold + QW for 16 a ----------------
        const int pb = blockIdx.x - D_M;   // 0..127
        const int h  = pb >> 4;
        const int a0 = (pb & 15) * 16;

        {
            const float4* w4 = (const float4*)(wq_w + h * D_V * D_V);
            #pragma unroll
            for (int i = 0; i < 4; i++) {
                int f = i * 256 + tid;
                float4 v = w4[f];
                int e = f >> 4, c = (f & 15) * 4;
                *(float4*)&wq_s[e][c] = v;
            }
        }
        {
            int al = tid >> 4, j0 = (tid & 15) * 4;
            float tv = (float)(a0 + al);
            #pragma unroll
            for (int j = 0; j < 4; j++) {
                int d = j0 + j;
                float f = t2v_w[h * D_V + d] * tv + t2v_phi[h * D_V + d];
                thA[al][d] = (d == 0) ? f : __sinf(f);
            }
        }
        __syncthreads();

        // Phase A: QaT[a][e] = thA[a] . wq_s[e] + wq_b[e]
        {
            const int e  = tid >> 2;
            const int ap = tid & 3;
            float accA[4] = {0.f, 0.f, 0.f, 0.f};
            const float4* wrow = (const float4*)&wq_s[e][0];
            #pragma unroll
            for (int j = 0; j < 16; j++) {
                float4 w = wrow[j];
                #pragma unroll
                for (int k = 0; k < 4; k++) {
                    float4 tv = *(const float4*)&thA[ap + 4 * k][j * 4];
                    accA[k] += w.x * tv.x + w.y * tv.y + w.z * tv.z + w.w * tv.w;
                }
            }
            float bq = wq_b[h * D_V + e];
            #pragma unroll
            for (int k = 0; k < 4; k++) QaT[ap + 4 * k][e] = accA[k] + bq;
        }
        __syncthreads();

        // Phase B: QW[d][a] = sum_e QaT[a][e] * wk_w[h][e][d]
        const int d  = tid >> 2;
        const int ap = tid & 3;
        float accB[4] = {0.f, 0.f, 0.f, 0.f};
        #pragma unroll 4
        for (int e4 = 0; e4 < 16; e4++) {
            const float* wkp = &wk_w[(h * D_V + e4 * 4) * D_V + d];
            float w0 = wkp[0];
            float w1 = wkp[D_V];
            float w2 = wkp[2 * D_V];
            float w3 = wkp[3 * D_V];
            #pragma unroll
            for (int k = 0; k < 4; k++) {
                float4 qv = *(const float4*)&QaT[ap + 4 * k][e4 * 4];
                accB[k] += qv.x * w0 + qv.y * w1 + qv.z * w2 + qv.w * w3;
            }
        }
        #pragma unroll
        for (int k = 0; k < 4; k++)
            QWbuf[h * D_V * ALPHA + d * ALPHA + a0 + ap + 4 * k] = accB[k];

        // QWabs reduction: wq_s reused as red[d][a-local]
        __syncthreads();
        #pragma unroll
        for (int k = 0; k < 4; k++)
            wq_s[d][ap + 4 * k] = (d == 0) ? 0.0f : fabsf(accB[k]);
        __syncthreads();
        if (tid < 16) {
            float s = 0.0f;
            #pragma unroll 8
            for (int dd = 0; dd < D_V; dd++) s += wq_s[dd][tid];
            QWabsG[h * ALPHA + a0 + tid] = s;
        }
    }
}

// ---------------------------------------------------------------------------
// Kernel 2: mTAND attention via MFMA, split over A (not l!) for occupancy:
// grid (2 a-halves, 64 m, 8 h) = 1024 blocks; each wave owns 2 a-tiles, so
// per-wave register state (A-frags + softmax sums) halves vs the 4-tile form
// (R14 lesson: VGPR=188 capped residency at 2 waves/SIMD; target <=128).
// a-split needs NO partials: softmax rows are independent in a.
// Double-buffered sin-fragment LDS: iteration lt reads tile lt's f16 frags
// (hi+res) from buf[cur] while all 256 threads write tile lt+1's 1024 sins
// into buf[cur^1] -- one barrier per tile, writer VALU overlaps reader MFMA.
// Bound-shifted softmax folded into the MFMA C-init; d=0 linear term exact
// in fp32; d>=1 via 3-term split-precision f16 MFMA (identical d-slot
// formula on A and B -> permutation-proof).
// ---------------------------------------------------------------------------
__global__ __launch_bounds__(256) void attn_mfma_kernel(
    const float* __restrict__ x_ts, const float* __restrict__ t_ts,
    const float* __restrict__ t2v_w, const float* __restrict__ t2v_phi,
    const float* __restrict__ QWbuf, const float* __restrict__ QWabsG,
    float* __restrict__ interp)
{
    const int ah  = blockIdx.x;          // a-half (128 a)
    const int m   = blockIdx.y;
    const int h   = blockIdx.z;
    const int tid = threadIdx.x;
    const int wv  = tid >> 6;
    const int ln  = tid & 63;
    const int lg  = ln >> 4;             // lane group (0..3)
    const int lc  = ln & 15;             // B col / A row within tile

    __shared__ float t_sh[L_OBS], x_sh[L_OBS], mk_sh[L_OBS];
    __shared__ float w_sh[D_V], phi_sh[D_V];
    __shared__ __align__(16) _Float16 hiB[2048];   // 4 KiB, 2 buffers
    __shared__ __align__(16) _Float16 reB[2048];   // 4 KiB, 2 buffers
    __shared__ float red_s[8];

    {
        float x = x_ts[m * L_OBS + tid];
        float t = t_ts[m * L_OBS + tid];
        bool v = (x == x) && (t >= 0.0f);
        x_sh[tid]  = v ? x : 0.0f;
        t_sh[tid]  = v ? t : 0.0f;
        mk_sh[tid] = v ? 0.0f : -1.0e9f;
        float tmx = v ? t : -3.0e38f;
        float tmn = v ? t : 3.0e38f;
        #pragma unroll
        for (int s = 1; s < 64; s <<= 1) {
            tmx = fmaxf(tmx, __shfl_xor(tmx, s));
            tmn = fminf(tmn, __shfl_xor(tmn, s));
        }
        if (ln == 0) { red_s[wv] = tmx; red_s[4 + wv] = tmn; }
    }
    if (tid < D_V)          w_sh[tid]         = t2v_w[h * D_V + tid];
    else if (tid < 2 * D_V) phi_sh[tid - D_V] = t2v_phi[h * D_V + tid - D_V];
    __syncthreads();

    const float tmaxv = fmaxf(fmaxf(red_s[0], red_s[1]), fmaxf(red_s[2], red_s[3]));
    const float tminv = fminf(fminf(red_s[4], red_s[5]), fminf(red_s[6], red_s[7]));
    const bool  anyv  = tmaxv > -1.0e37f;

    const float* __restrict__ QWh = QWbuf + h * D_V * ALPHA;
    const float w0 = w_sh[0], p0 = phi_sh[0];
    const float SCALE2 = 0.18033688011112042f;   // 0.125 * log2(e)

    // ---- stage A fragments (hi + residual) + bound-folded C-init, 2 tiles ----
    half8 ahf[2][2], arf[2][2];
    float qw0[2][4], c0b[2][4];
    #pragma unroll
    for (int at = 0; at < 2; at++) {
        const int abase = ah * 128 + wv * 32 + at * 16;
        const int arowA = abase + lc;
        #pragma unroll
        for (int kb = 0; kb < 2; kb++) {
            #pragma unroll
            for (int j = 0; j < 8; j++) {
                int d = 1 + kb * 32 + ((j >> 2) << 4) + (lg << 2) + (j & 3);
                float q = (d < D_V) ? QWh[d * ALPHA + arowA] : 0.0f;
                _Float16 qh = (_Float16)q;
                ahf[at][kb][j] = qh;
                arf[at][kb][j] = (_Float16)(q - (float)qh);
            }
        }
        const int arowD = abase + lg * 4;
        #pragma unroll
        for (int r = 0; r < 4; r++) {
            float q0 = QWh[arowD + r];
            qw0[at][r] = q0;
            float u = q0 * w0;
            float lin = q0 * p0 + fmaxf(u * tmaxv, u * tminv);
            c0b[at][r] = -(lin + QWabsG[h * ALPHA + arowD + r]);
        }
    }

    float ssum[2][4], axs[2][4];
    #pragma unroll
    for (int at = 0; at < 2; at++)
        #pragma unroll
        for (int r = 0; r < 4; r++) { ssum[at][r] = 0.0f; axs[at][r] = 0.0f; }

    // writer-role constants (layout verified: matches reader fi formula)
    const int wc  = tid >> 5;                 // combo = kb*4+lg, 0..7
    const int lcw = (tid >> 1) & 15;          // l within tile
    const int dB  = 1 + (wc >> 2) * 32 + (wc & 3) * 4 + ((tid & 1) << 4);

    auto write_frags = [&](int lt, int buf) {
        float tvw = t_sh[lt * 16 + lcw];
        float s0 = __sinf(fmaf(w_sh[(dB + 0) & 63], tvw, phi_sh[(dB + 0) & 63]));
        float s1 = __sinf(fmaf(w_sh[(dB + 1) & 63], tvw, phi_sh[(dB + 1) & 63]));
        float s2 = __sinf(fmaf(w_sh[(dB + 2) & 63], tvw, phi_sh[(dB + 2) & 63]));
        float s3 = __sinf(fmaf(w_sh[(dB + 3) & 63], tvw, phi_sh[(dB + 3) & 63]));
        union { _Float16 hv[4]; float2 f2; } hw, rw;
        hw.hv[0] = (_Float16)s0; hw.hv[1] = (_Float16)s1;
        hw.hv[2] = (_Float16)s2; hw.hv[3] = (_Float16)s3;
        rw.hv[0] = (_Float16)(s0 - (float)hw.hv[0]);
        rw.hv[1] = (_Float16)(s1 - (float)hw.hv[1]);
        rw.hv[2] = (_Float16)(s2 - (float)hw.hv[2]);
        rw.hv[3] = (_Float16)(s3 - (float)hw.hv[3]);
        *(float2*)&hiB[buf * 1024 + tid * 4] = hw.f2;
        *(float2*)&reB[buf * 1024 + tid * 4] = rw.f2;
    };

    // prologue: tile 0 into buffer 0
    write_frags(0, 0);
    __syncthreads();

    // ---- main loop over 16 l-tiles, one barrier each ----
    for (int lt = 0; lt < 16; lt++) {
        const int cur = lt & 1;
        half8 bh[2], br[2];
        #pragma unroll
        for (int kb = 0; kb < 2; kb++) {
            int fi = cur * 1024 + ((kb * 4 + lg) * 16 + lc) * 8;
            bh[kb] = *(const half8*)&hiB[fi];
            br[kb] = *(const half8*)&reB[fi];
        }
        if (lt < 15) write_frags(lt + 1, cur ^ 1);

        const int l = lt * 16 + lc;
        const float tv  = t_sh[l];
        const float xv  = x_sh[l];
        const float mkv = mk_sh[l];
        const float tau = fmaf(w0, tv, p0);

        #pragma unroll
        for (int at = 0; at < 2; at++) {
            f32x4 acc;
            #pragma unroll
            for (int r = 0; r < 4; r++)
                acc[r] = fmaf(qw0[at][r], tau, c0b[at][r]);  // exact d=0 - bound
            #pragma unroll
            for (int kb = 0; kb < 2; kb++) {
                acc = __builtin_amdgcn_mfma_f32_16x16x32_f16(ahf[at][kb], bh[kb], acc, 0, 0, 0);
                acc = __builtin_amdgcn_mfma_f32_16x16x32_f16(ahf[at][kb], br[kb], acc, 0, 0, 0);
                acc = __builtin_amdgcn_mfma_f32_16x16x32_f16(arf[at][kb], bh[kb], acc, 0, 0, 0);
            }
            #pragma unroll
            for (int r = 0; r < 4; r++) {
                float p = __builtin_amdgcn_exp2f(fmaf(acc[r], SCALE2, mkv));
                ssum[at][r] += p;
                axs[at][r]   = fmaf(p, xv, axs[at][r]);
            }
        }
        __syncthreads();
    }

    // ---- merge across the 16 lc lanes, write interp [a][m][h] ----
    #pragma unroll
    for (int at = 0; at < 2; at++) {
        #pragma unroll
        for (int r = 0; r < 4; r++) {
            float S = ssum[at][r];
            float A = axs[at][r];
            S += __shfl_xor(S, 1); A += __shfl_xor(A, 1);
            S += __shfl_xor(S, 2); A += __shfl_xor(A, 2);
            S += __shfl_xor(S, 4); A += __shfl_xor(A, 4);
            S += __shfl_xor(S, 8); A += __shfl_xor(A, 8);
            if (lc == 0) {
                int a = ah * 128 + wv * 32 + at * 16 + lg * 4 + r;
                interp[a * (D_M * N_HEADS) + m * N_HEADS + h] =
                    anyv ? (A / S) : 0.0f;
            }
        }
    }
}

// ---------------------------------------------------------------------------
// Kernel 3: fused e_imp + e_attn + gate MLP + output. Block per a, 256 thr
// (the proven-parallel config; grid 256 keeps weight streaming latency
// hidden by block-level parallelism).
// ---------------------------------------------------------------------------
__global__ __launch_bounds__(256) void final_kernel(
    const float* __restrict__ regular, const float* __restrict__ interp,
    const float* __restrict__ conv_w, const float* __restrict__ conv_b,
    const float* __restrict__ proj_w, const float* __restrict__ proj_b,
    const float* __restrict__ g1_w, const float* __restrict__ g1_b,
    const float* __restrict__ g2_w, const float* __restrict__ g2_b,
    float* __restrict__ out)
{
    const int a = blockIdx.x;
    const int tid = threadIdx.x;
    __shared__ float isum_s[N_HEADS];
    __shared__ __align__(16) float col[D_M];
    __shared__ __align__(16) float c_s[2 * D_H];
    __shared__ __align__(16) float h_s[D_H];

    if (tid < 64) {
        const float4* i4 = (const float4*)&interp[a * (D_M * N_HEADS) + tid * 8];
        float4 v0 = i4[0], v1 = i4[1];
        float v[8] = {v0.x, v0.y, v0.z, v0.w, v1.x, v1.y, v1.z, v1.w};
        #pragma unroll
        for (int s = 1; s < 64; s <<= 1) {
            #pragma unroll
            for (int j = 0; j < 8; j++) v[j] += __shfl_xor(v[j], s);
        }
        if (tid == 0) {
            #pragma unroll
            for (int j = 0; j < 8; j++) isum_s[j] = v[j];
        }
    } else if (tid < 128) {
        col[tid - 64] = regular[(tid - 64) * ALPHA + a];
    }
    __syncthreads();

    float vattn;
    {
        const float4* p4 = (const float4*)&proj_w[tid * N_HEADS];
        float4 v0 = p4[0], v1 = p4[1];
        float sum = v0.x * isum_s[0] + v0.y * isum_s[1] + v0.z * isum_s[2]
                  + v0.w * isum_s[3] + v1.x * isum_s[4] + v1.y * isum_s[5]
                  + v1.z * isum_s[6] + v1.w * isum_s[7];
        vattn = proj_b[tid] + sum * (1.0f / 64.0f);
    }
    float vimp;
    {
        const float4* row = (const float4*)&conv_w[tid * D_M];
        const float4* c4  = (const float4*)col;
        float s0 = 0.f, s1 = 0.f, s2 = 0.f, s3 = 0.f;
        #pragma unroll
        for (int i = 0; i < D_M / 4; i++) {
            float4 r = row[i]; float4 c = c4[i];
            s0 += r.x * c.x; s1 += r.y * c.y; s2 += r.z * c.z; s3 += r.w * c.w;
        }
        vimp = conv_b[tid] + ((s0 + s1) + (s2 + s3));
    }
    c_s[tid]       = vimp;
    c_s[D_H + tid] = vattn;
    __syncthreads();

    {
        const float4* grow = (const float4*)&g1_w[tid * 2 * D_H];
        const float4* c4 = (const float4*)c_s;
        float s0 = 0.f, s1 = 0.f, s2 = 0.f, s3 = 0.f;
        #pragma unroll 8
        for (int i = 0; i < (2 * D_H) / 4; i++) {
            float4 g = grow[i]; float4 c = c4[i];
            s0 += g.x * c.x; s1 += g.y * c.y; s2 += g.z * c.z; s3 += g.w * c.w;
        }
        float hid = g1_b[tid] + ((s0 + s1) + (s2 + s3));
        h_s[tid] = fmaxf(hid, 0.0f);
    }
    __syncthreads();
    {
        const float4* grow = (const float4*)&g2_w[tid * D_H];
        const float4* h4 = (const float4*)h_s;
        float s0 = 0.f, s1 = 0.f, s2 = 0.f, s3 = 0.f;
        #pragma unroll 8
        for (int i = 0; i < D_H / 4; i++) {
            float4 g = grow[i]; float4 hh = h4[i];
            s0 += g.x * hh.x; s1 += g.y * hh.y; s2 += g.z * hh.z; s3 += g.w * hh.w;
        }
        float z = g2_b[tid] + ((s0 + s1) + (s2 + s3));
        float gate = 1.0f / (1.0f + __expf(-z));
        out[a * D_H + tid] = gate * vimp + (1.0f - gate) * vattn;
    }
}

// ---------------------------------------------------------------------------
extern "C" void kernel_launch(void* const* d_in, const int* in_sizes, int n_in,
                              void* d_out, int out_size, void* d_ws, size_t ws_size,
                              hipStream_t stream)
{
    (void)in_sizes; (void)n_in; (void)out_size; (void)ws_size;

    const float* x_ts    = (const float*)d_in[0];
    const float* t_ts    = (const float*)d_in[1];
    const float* gm      = (const float*)d_in[2];
    const float* conv_w  = (const float*)d_in[3];
    const float* conv_b  = (const float*)d_in[4];
    const float* t2v_w   = (const float*)d_in[5];
    const float* t2v_phi = (const float*)d_in[6];
    const float* wq_w    = (const float*)d_in[7];
    const float* wq_b    = (const float*)d_in[8];
    const float* wk_w    = (const float*)d_in[9];
    const float* proj_w  = (const float*)d_in[11];
    const float* proj_b  = (const float*)d_in[12];
    const float* g1_w    = (const float*)d_in[13];
    const float* g1_b    = (const float*)d_in[14];
    const float* g2_w    = (const float*)d_in[15];
    const float* g2_b    = (const float*)d_in[16];

    float* out = (float*)d_out;

    float* ws      = (float*)d_ws;
    float* regular = ws;                               // 16384
    float* QWbuf   = regular + D_M * ALPHA;            // 131072  [h][d][a]
    float* interp  = QWbuf + N_HEADS * D_V * ALPHA;    // 131072  [a][m][h]
    float* QWabs   = interp + ALPHA * D_M * N_HEADS;   // 2048    [h][a]

    prep_kernel<<<D_M + 128, 256, 0, stream>>>(
        x_ts, t_ts, gm, t2v_w, t2v_phi, wq_w, wq_b, wk_w,
        regular, QWbuf, QWabs);
    attn_mfma_kernel<<<dim3(2, D_M, N_HEADS), 256, 0, stream>>>(
        x_ts, t_ts, t2v_w, t2v_phi, QWbuf, QWabs, interp);
    final_kernel<<<ALPHA, 256, 0, stream>>>(
        regular, interp, conv_w, conv_b, proj_w, proj_b,
        g1_w, g1_b, g2_w, g2_b, out);
}

// Round 16
// 52.721 us; speedup vs baseline: 1.4287x; 1.0923x over previous
//
#include <hip/hip_runtime.h>

#define D_M     64
#define L_OBS   256
#define ALPHA   256
#define D_H     256
#define D_V     64
#define N_HEADS 8

typedef _Float16 half8 __attribute__((ext_vector_type(8)));
typedef float    f32x4 __attribute__((ext_vector_type(4)));

// ---------------------------------------------------------------------------
// Kernel 1: prep. Blocks 0..63: per-row imputation (wave-scan cummax).
// Blocks 64..191: per-(h, 16-a-chunk) fold: Qa = theta_a.wq^T + wq_b,
// QW[d][a] = Qa.wk[.][d]; also QWabs[a] = sum_{d>=1} |QW[d][a]| (softmax bound).
// ---------------------------------------------------------------------------
__global__ __launch_bounds__(256) void prep_kernel(
    const float* __restrict__ x_ts, const float* __restrict__ t_ts,
    const float* __restrict__ gm,
    const float* __restrict__ t2v_w, const float* __restrict__ t2v_phi,
    const float* __restrict__ wq_w, const float* __restrict__ wq_b,
    const float* __restrict__ wk_w,
    float* __restrict__ regular, float* __restrict__ QWbuf,
    float* __restrict__ QWabsG)
{
    const int tid = threadIdx.x;

    __shared__ int   last[ALPHA];
    __shared__ float vals[ALPHA];
    __shared__ int   wtot[4];
    __shared__ __align__(16) float wq_s[D_V][68];
    __shared__ __align__(16) float thA[16][68];
    __shared__ __align__(16) float QaT[16][68];

    if (blockIdx.x < D_M) {
        // ---------------- imputation ----------------
        const int m  = blockIdx.x;
        const int l  = tid;
        const int wv = tid >> 6;
        const int ln = tid & 63;
        last[l] = -1;
        __syncthreads();
        float x = x_ts[m * L_OBS + l];
        float t = t_ts[m * L_OBS + l];
        bool valid = (x == x) && (t >= 0.0f);
        int idx = (int)t;
        if (valid && idx < ALPHA) atomicMax(&last[idx], l);
        __syncthreads();
        int li = last[l];
        vals[l] = (li >= 0) ? x_ts[m * L_OBS + li] : 0.0f;
        int p = (li >= 0) ? l : -1;
        #pragma unroll
        for (int s = 1; s < 64; s <<= 1) {
            int q = __shfl_up(p, s);
            if (ln >= s && q > p) p = q;
        }
        if (ln == 63) wtot[wv] = p;
        __syncthreads();
        int pre = -1;
        for (int w = 0; w < 4; w++)
            if (w < wv && wtot[w] > pre) pre = wtot[w];
        int lp = (pre > p) ? pre : p;
        regular[m * ALPHA + l] = (lp >= 0) ? vals[lp] : gm[m];
    } else {
        // ---------------- weight fold + QW for 16 a ----------------
        const int pb = blockIdx.x - D_M;   // 0..127
        const int h  = pb >> 4;
        const int a0 = (pb & 15) * 16;

        {
            const float4* w4 = (const float4*)(wq_w + h * D_V * D_V);
            #pragma unroll
            for (int i = 0; i < 4; i++) {
                int f = i * 256 + tid;
                float4 v = w4[f];
                int e = f >> 4, c = (f & 15) * 4;
                *(float4*)&wq_s[e][c] = v;
            }
        }
        {
            int al = tid >> 4, j0 = (tid & 15) * 4;
            float tv = (float)(a0 + al);
            #pragma unroll
            for (int j = 0; j < 4; j++) {
                int d = j0 + j;
                float f = t2v_w[h * D_V + d] * tv + t2v_phi[h * D_V + d];
                thA[al][d] = (d == 0) ? f : __sinf(f);
            }
        }
        __syncthreads();

        // Phase A: QaT[a][e] = thA[a] . wq_s[e] + wq_b[e]
        {
            const int e  = tid >> 2;
            const int ap = tid & 3;
            float accA[4] = {0.f, 0.f, 0.f, 0.f};
            const float4* wrow = (const float4*)&wq_s[e][0];
            #pragma unroll
            for (int j = 0; j < 16; j++) {
                float4 w = wrow[j];
                #pragma unroll
                for (int k = 0; k < 4; k++) {
                    float4 tv = *(const float4*)&thA[ap + 4 * k][j * 4];
                    accA[k] += w.x * tv.x + w.y * tv.y + w.z * tv.z + w.w * tv.w;
                }
            }
            float bq = wq_b[h * D_V + e];
            #pragma unroll
            for (int k = 0; k < 4; k++) QaT[ap + 4 * k][e] = accA[k] + bq;
        }
        __syncthreads();

        // Phase B: QW[d][a] = sum_e QaT[a][e] * wk_w[h][e][d]
        const int d  = tid >> 2;
        const int ap = tid & 3;
        float accB[4] = {0.f, 0.f, 0.f, 0.f};
        #pragma unroll 4
        for (int e4 = 0; e4 < 16; e4++) {
            const float* wkp = &wk_w[(h * D_V + e4 * 4) * D_V + d];
            float w0 = wkp[0];
            float w1 = wkp[D_V];
            float w2 = wkp[2 * D_V];
            float w3 = wkp[3 * D_V];
            #pragma unroll
            for (int k = 0; k < 4; k++) {
                float4 qv = *(const float4*)&QaT[ap + 4 * k][e4 * 4];
                accB[k] += qv.x * w0 + qv.y * w1 + qv.z * w2 + qv.w * w3;
            }
        }
        #pragma unroll
        for (int k = 0; k < 4; k++)
            QWbuf[h * D_V * ALPHA + d * ALPHA + a0 + ap + 4 * k] = accB[k];

        // QWabs reduction: wq_s reused as red[d][a-local]
        __syncthreads();
        #pragma unroll
        for (int k = 0; k < 4; k++)
            wq_s[d][ap + 4 * k] = (d == 0) ? 0.0f : fabsf(accB[k]);
        __syncthreads();
        if (tid < 16) {
            float s = 0.0f;
            #pragma unroll 8
            for (int dd = 0; dd < D_V; dd++) s += wq_s[dd][tid];
            QWabsG[h * ALPHA + a0 + tid] = s;
        }
    }
}

// ---------------------------------------------------------------------------
// Kernel 2: mTAND attention via MFMA + VALID-OBSERVATION COMPACTION.
// Grid (2 ah, 64 m, 8 h); 256 thr = 4 waves; each wave owns 2 a-tiles.
// Compaction (ballot/popc, R6-proven): valid obs scattered to xc/tc front;
// main loop runs nst = ceil(Lv/16) tiles (E~8.5 vs 16), tail slots masked
// -1e9 -> exp2 = 0 (exact; pure f32 sum reorder).
// 2 l-tiles per barrier REGION with double-buffered 2-tile sin-frag LDS:
// region rg reads buf[rg&1], writes region rg+1's sins into buf[rg&1 ^1]
// (writes issued before computes -> sin VALU overlaps MFMA), ONE barrier
// per region (~5 expected vs 16).
// Bound-shifted softmax folded into MFMA C-init; d=0 linear term exact in
// fp32; d>=1 via 3-term split-precision f16 MFMA (identical d-slot formula
// on A and B -> permutation-proof).
// ---------------------------------------------------------------------------
__global__ __launch_bounds__(256) void attn_mfma_kernel(
    const float* __restrict__ x_ts, const float* __restrict__ t_ts,
    const float* __restrict__ t2v_w, const float* __restrict__ t2v_phi,
    const float* __restrict__ QWbuf, const float* __restrict__ QWabsG,
    float* __restrict__ interp)
{
    const int ah  = blockIdx.x;          // a-half (128 a)
    const int m   = blockIdx.y;
    const int h   = blockIdx.z;
    const int tid = threadIdx.x;
    const int wv  = tid >> 6;
    const int ln  = tid & 63;
    const int lg  = ln >> 4;             // lane group (0..3)
    const int lc  = ln & 15;             // B col / A row within tile

    __shared__ float xc[L_OBS], tc[L_OBS];          // compacted obs
    __shared__ float w_sh[D_V], phi_sh[D_V];
    __shared__ __align__(16) _Float16 hiB[2][2048]; // 8 KiB (2 buf x 2 tiles)
    __shared__ __align__(16) _Float16 reB[2][2048]; // 8 KiB
    __shared__ float red_s[8];
    __shared__ int   cnt_s[4];

    // init pads + staging
    xc[tid] = 0.0f;
    tc[tid] = 0.0f;
    float x = x_ts[m * L_OBS + tid];
    float t = t_ts[m * L_OBS + tid];
    bool  v = (x == x) && (t >= 0.0f);
    unsigned long long bal = __ballot(v);
    if (ln == 0) cnt_s[wv] = __popcll(bal);
    {
        float tmx = v ? t : -3.0e38f;
        float tmn = v ? t : 3.0e38f;
        #pragma unroll
        for (int s = 1; s < 64; s <<= 1) {
            tmx = fmaxf(tmx, __shfl_xor(tmx, s));
            tmn = fminf(tmn, __shfl_xor(tmn, s));
        }
        if (ln == 0) { red_s[wv] = tmx; red_s[4 + wv] = tmn; }
    }
    if (tid < D_V)          w_sh[tid]         = t2v_w[h * D_V + tid];
    else if (tid < 2 * D_V) phi_sh[tid - D_V] = t2v_phi[h * D_V + tid - D_V];
    __syncthreads();   // pads + cnt_s + red_s + w/phi visible

    const int c0 = cnt_s[0], c1 = cnt_s[1], c2 = cnt_s[2], c3 = cnt_s[3];
    const int Lv = c0 + c1 + c2 + c3;
    {
        int base = (wv > 0 ? c0 : 0) + (wv > 1 ? c1 : 0) + (wv > 2 ? c2 : 0);
        unsigned long long lm = (1ull << ln) - 1ull;
        if (v) { int p = base + __popcll(bal & lm); xc[p] = x; tc[p] = t; }
    }

    const float tmaxv = fmaxf(fmaxf(red_s[0], red_s[1]), fmaxf(red_s[2], red_s[3]));
    const float tminv = fminf(fminf(red_s[4], red_s[5]), fminf(red_s[6], red_s[7]));
    const bool  anyv  = tmaxv > -1.0e37f;

    const float* __restrict__ QWh = QWbuf + h * D_V * ALPHA;
    const float w0 = w_sh[0], p0 = phi_sh[0];
    const float SCALE2 = 0.18033688011112042f;   // 0.125 * log2(e)

    // ---- stage A fragments (hi + residual) + bound-folded C-init, 2 tiles ----
    half8 ahf[2][2], arf[2][2];
    float qw0[2][4], c0b[2][4];
    #pragma unroll
    for (int at = 0; at < 2; at++) {
        const int abase = ah * 128 + wv * 32 + at * 16;
        const int arowA = abase + lc;
        #pragma unroll
        for (int kb = 0; kb < 2; kb++) {
            #pragma unroll
            for (int j = 0; j < 8; j++) {
                int d = 1 + kb * 32 + ((j >> 2) << 4) + (lg << 2) + (j & 3);
                float q = (d < D_V) ? QWh[d * ALPHA + arowA] : 0.0f;
                _Float16 qh = (_Float16)q;
                ahf[at][kb][j] = qh;
                arf[at][kb][j] = (_Float16)(q - (float)qh);
            }
        }
        const int arowD = abase + lg * 4;
        #pragma unroll
        for (int r = 0; r < 4; r++) {
            float q0 = QWh[arowD + r];
            qw0[at][r] = q0;
            float u = q0 * w0;
            float lin = q0 * p0 + fmaxf(u * tmaxv, u * tminv);
            c0b[at][r] = -(lin + QWabsG[h * ALPHA + arowD + r]);
        }
    }

    float ssum[2][4], axs[2][4];
    #pragma unroll
    for (int at = 0; at < 2; at++)
        #pragma unroll
        for (int r = 0; r < 4; r++) { ssum[at][r] = 0.0f; axs[at][r] = 0.0f; }

    // writer-role constants (same frag layout as reader fi formula)
    const int wc  = tid >> 5;                 // combo = kb*4+lg, 0..7
    const int lcw = (tid >> 1) & 15;          // l within tile
    const int dB  = 1 + (wc >> 2) * 32 + (wc & 3) * 4 + ((tid & 1) << 4);

    auto write_frags = [&](int lt, int buf, int slot) {
        float tvw = tc[lt * 16 + lcw];
        float s0 = __sinf(fmaf(w_sh[(dB + 0) & 63], tvw, phi_sh[(dB + 0) & 63]));
        float s1 = __sinf(fmaf(w_sh[(dB + 1) & 63], tvw, phi_sh[(dB + 1) & 63]));
        float s2 = __sinf(fmaf(w_sh[(dB + 2) & 63], tvw, phi_sh[(dB + 2) & 63]));
        float s3 = __sinf(fmaf(w_sh[(dB + 3) & 63], tvw, phi_sh[(dB + 3) & 63]));
        union { _Float16 hv[4]; float2 f2; } hw, rw;
        hw.hv[0] = (_Float16)s0; hw.hv[1] = (_Float16)s1;
        hw.hv[2] = (_Float16)s2; hw.hv[3] = (_Float16)s3;
        rw.hv[0] = (_Float16)(s0 - (float)hw.hv[0]);
        rw.hv[1] = (_Float16)(s1 - (float)hw.hv[1]);
        rw.hv[2] = (_Float16)(s2 - (float)hw.hv[2]);
        rw.hv[3] = (_Float16)(s3 - (float)hw.hv[3]);
        *(float2*)&hiB[buf][slot * 1024 + tid * 4] = hw.f2;
        *(float2*)&reB[buf][slot * 1024 + tid * 4] = rw.f2;
    };

    const int nst  = (Lv + 15) >> 4;     // tiles of 16 compacted l
    const int nreg = (nst + 1) >> 1;     // 2-tile barrier regions

    __syncthreads();   // scatter (xc/tc) visible before prologue sins
    write_frags(0, 0, 0);
    write_frags(1, 0, 1);
    __syncthreads();

    // ---- main loop: one barrier per 2-tile region ----
    for (int rg = 0; rg < nreg; rg++) {
        const int cur = rg & 1;
        // issue next region's sin-writes first (overlaps MFMA below)
        if (rg + 1 < nreg) {
            write_frags(2 * rg + 2, cur ^ 1, 0);
            write_frags(2 * rg + 3, cur ^ 1, 1);
        }
        #pragma unroll
        for (int s = 0; s < 2; s++) {
            const int st = 2 * rg + s;
            if (st >= nst) break;   // block-uniform (Lv shared)
            half8 bh[2], br[2];
            #pragma unroll
            for (int kb = 0; kb < 2; kb++) {
                int fi = s * 1024 + ((kb * 4 + lg) * 16 + lc) * 8;
                bh[kb] = *(const half8*)&hiB[cur][fi];
                br[kb] = *(const half8*)&reB[cur][fi];
            }
            const int l = st * 16 + lc;
            const float tv  = tc[l];
            const float xv  = xc[l];
            const float mkv = (l < Lv) ? 0.0f : -1.0e9f;
            const float tau = fmaf(w0, tv, p0);

            #pragma unroll
            for (int at = 0; at < 2; at++) {
                f32x4 acc;
                #pragma unroll
                for (int r = 0; r < 4; r++)
                    acc[r] = fmaf(qw0[at][r], tau, c0b[at][r]);  // exact d=0 - bound
                #pragma unroll
                for (int kb = 0; kb < 2; kb++) {
                    acc = __builtin_amdgcn_mfma_f32_16x16x32_f16(ahf[at][kb], bh[kb], acc, 0, 0, 0);
                    acc = __builtin_amdgcn_mfma_f32_16x16x32_f16(ahf[at][kb], br[kb], acc, 0, 0, 0);
                    acc = __builtin_amdgcn_mfma_f32_16x16x32_f16(arf[at][kb], bh[kb], acc, 0, 0, 0);
                }
                #pragma unroll
                for (int r = 0; r < 4; r++) {
                    float p = __builtin_amdgcn_exp2f(fmaf(acc[r], SCALE2, mkv));
                    ssum[at][r] += p;
                    axs[at][r]   = fmaf(p, xv, axs[at][r]);
                }
            }
        }
        __syncthreads();
    }

    // ---- merge across the 16 lc lanes, write interp [a][m][h] ----
    #pragma unroll
    for (int at = 0; at < 2; at++) {
        #pragma unroll
        for (int r = 0; r < 4; r++) {
            float S = ssum[at][r];
            float A = axs[at][r];
            S += __shfl_xor(S, 1); A += __shfl_xor(A, 1);
            S += __shfl_xor(S, 2); A += __shfl_xor(A, 2);
            S += __shfl_xor(S, 4); A += __shfl_xor(A, 4);
            S += __shfl_xor(S, 8); A += __shfl_xor(A, 8);
            if (lc == 0) {
                int a = ah * 128 + wv * 32 + at * 16 + lg * 4 + r;
                interp[a * (D_M * N_HEADS) + m * N_HEADS + h] =
                    anyv ? (A / S) : 0.0f;
            }
        }
    }
}

// ---------------------------------------------------------------------------
// Kernel 3: fused e_imp + e_attn + gate MLP + output. Block per a, 256 thr.
// ---------------------------------------------------------------------------
__global__ __launch_bounds__(256) void final_kernel(
    const float* __restrict__ regular, const float* __restrict__ interp,
    const float* __restrict__ conv_w, const float* __restrict__ conv_b,
    const float* __restrict__ proj_w, const float* __restrict__ proj_b,
    const float* __restrict__ g1_w, const float* __restrict__ g1_b,
    const float* __restrict__ g2_w, const float* __restrict__ g2_b,
    float* __restrict__ out)
{
    const int a = blockIdx.x;
    const int tid = threadIdx.x;
    __shared__ float isum_s[N_HEADS];
    __shared__ __align__(16) float col[D_M];
    __shared__ __align__(16) float c_s[2 * D_H];
    __shared__ __align__(16) float h_s[D_H];

    if (tid < 64) {
        const float4* i4 = (const float4*)&interp[a * (D_M * N_HEADS) + tid * 8];
        float4 v0 = i4[0], v1 = i4[1];
        float v[8] = {v0.x, v0.y, v0.z, v0.w, v1.x, v1.y, v1.z, v1.w};
        #pragma unroll
        for (int s = 1; s < 64; s <<= 1) {
            #pragma unroll
            for (int j = 0; j < 8; j++) v[j] += __shfl_xor(v[j], s);
        }
        if (tid == 0) {
            #pragma unroll
            for (int j = 0; j < 8; j++) isum_s[j] = v[j];
        }
    } else if (tid < 128) {
        col[tid - 64] = regular[(tid - 64) * ALPHA + a];
    }
    __syncthreads();

    float vattn;
    {
        const float4* p4 = (const float4*)&proj_w[tid * N_HEADS];
        float4 v0 = p4[0], v1 = p4[1];
        float sum = v0.x * isum_s[0] + v0.y * isum_s[1] + v0.z * isum_s[2]
                  + v0.w * isum_s[3] + v1.x * isum_s[4] + v1.y * isum_s[5]
                  + v1.z * isum_s[6] + v1.w * isum_s[7];
        vattn = proj_b[tid] + sum * (1.0f / 64.0f);
    }
    float vimp;
    {
        const float4* row = (const float4*)&conv_w[tid * D_M];
        const float4* c4  = (const float4*)col;
        float s0 = 0.f, s1 = 0.f, s2 = 0.f, s3 = 0.f;
        #pragma unroll
        for (int i = 0; i < D_M / 4; i++) {
            float4 r = row[i]; float4 c = c4[i];
            s0 += r.x * c.x; s1 += r.y * c.y; s2 += r.z * c.z; s3 += r.w * c.w;
        }
        vimp = conv_b[tid] + ((s0 + s1) + (s2 + s3));
    }
    c_s[tid]       = vimp;
    c_s[D_H + tid] = vattn;
    __syncthreads();

    {
        const float4* grow = (const float4*)&g1_w[tid * 2 * D_H];
        const float4* c4 = (const float4*)c_s;
        float s0 = 0.f, s1 = 0.f, s2 = 0.f, s3 = 0.f;
        #pragma unroll 8
        for (int i = 0; i < (2 * D_H) / 4; i++) {
            float4 g = grow[i]; float4 c = c4[i];
            s0 += g.x * c.x; s1 += g.y * c.y; s2 += g.z * c.z; s3 += g.w * c.w;
        }
        float hid = g1_b[tid] + ((s0 + s1) + (s2 + s3));
        h_s[tid] = fmaxf(hid, 0.0f);
    }
    __syncthreads();
    {
        const float4* grow = (const float4*)&g2_w[tid * D_H];
        const float4* h4 = (const float4*)h_s;
        float s0 = 0.f, s1 = 0.f, s2 = 0.f, s3 = 0.f;
        #pragma unroll 8
        for (int i = 0; i < D_H / 4; i++) {
            float4 g = grow[i]; float4 hh = h4[i];
            s0 += g.x * hh.x; s1 += g.y * hh.y; s2 += g.z * hh.z; s3 += g.w * hh.w;
        }
        float z = g2_b[tid] + ((s0 + s1) + (s2 + s3));
        float gate = 1.0f / (1.0f + __expf(-z));
        out[a * D_H + tid] = gate * vimp + (1.0f - gate) * vattn;
    }
}

// ---------------------------------------------------------------------------
extern "C" void kernel_launch(void* const* d_in, const int* in_sizes, int n_in,
                              void* d_out, int out_size, void* d_ws, size_t ws_size,
                              hipStream_t stream)
{
    (void)in_sizes; (void)n_in; (void)out_size; (void)ws_size;

    const float* x_ts    = (const float*)d_in[0];
    const float* t_ts    = (const float*)d_in[1];
    const float* gm      = (const float*)d_in[2];
    const float* conv_w  = (const float*)d_in[3];
    const float* conv_b  = (const float*)d_in[4];
    const float* t2v_w   = (const float*)d_in[5];
    const float* t2v_phi = (const float*)d_in[6];
    const float* wq_w    = (const float*)d_in[7];
    const float* wq_b    = (const float*)d_in[8];
    const float* wk_w    = (const float*)d_in[9];
    const float* proj_w  = (const float*)d_in[11];
    const float* proj_b  = (const float*)d_in[12];
    const float* g1_w    = (const float*)d_in[13];
    const float* g1_b    = (const float*)d_in[14];
    const float* g2_w    = (const float*)d_in[15];
    const float* g2_b    = (const float*)d_in[16];

    float* out = (float*)d_out;

    float* ws      = (float*)d_ws;
    float* regular = ws;                               // 16384
    float* QWbuf   = regular + D_M * ALPHA;            // 131072  [h][d][a]
    float* interp  = QWbuf + N_HEADS * D_V * ALPHA;    // 131072  [a][m][h]
    float* QWabs   = interp + ALPHA * D_M * N_HEADS;   // 2048    [h][a]

    prep_kernel<<<D_M + 128, 256, 0, stream>>>(
        x_ts, t_ts, gm, t2v_w, t2v_phi, wq_w, wq_b, wk_w,
        regular, QWbuf, QWabs);
    attn_mfma_kernel<<<dim3(2, D_M, N_HEADS), 256, 0, stream>>>(
        x_ts, t_ts, t2v_w, t2v_phi, QWbuf, QWabs, interp);
    final_kernel<<<ALPHA, 256, 0, stream>>>(
        regular, interp, conv_w, conv_b, proj_w, proj_b,
        g1_w, g1_b, g2_w, g2_b, out);
}

// Round 17
// 51.612 us; speedup vs baseline: 1.4594x; 1.0215x over previous
//
#include <hip/hip_runtime.h>

#define D_M     64
#define L_OBS   256
#define ALPHA   256
#define D_H     256
#define D_V     64
#define N_HEADS 8

typedef _Float16 half8 __attribute__((ext_vector_type(8)));
typedef float    f32x4 __attribute__((ext_vector_type(4)));

// ---------------------------------------------------------------------------
// Kernel 1: prep. Blocks 0..63: per-row imputation (wave-scan cummax).
// Blocks 64..191: per-(h, 16-a-chunk) fold: Qa = theta_a.wq^T + wq_b,
// QW[d][a] = Qa.wk[.][d]; also QWabs[a] = sum_{d>=1} |QW[d][a]| (softmax bound).
// ---------------------------------------------------------------------------
__global__ __launch_bounds__(256) void prep_kernel(
    const float* __restrict__ x_ts, const float* __restrict__ t_ts,
    const float* __restrict__ gm,
    const float* __restrict__ t2v_w, const float* __restrict__ t2v_phi,
    const float* __restrict__ wq_w, const float* __restrict__ wq_b,
    const float* __restrict__ wk_w,
    float* __restrict__ regular, float* __restrict__ QWbuf,
    float* __restrict__ QWabsG)
{
    const int tid = threadIdx.x;

    __shared__ int   last[ALPHA];
    __shared__ float vals[ALPHA];
    __shared__ int   wtot[4];
    __shared__ __align__(16) float wq_s[D_V][68];
    __shared__ __align__(16) float thA[16][68];
    __shared__ __align__(16) float QaT[16][68];

    if (blockIdx.x < D_M) {
        // ---------------- imputation ----------------
        const int m  = blockIdx.x;
        const int l  = tid;
        const int wv = tid >> 6;
        const int ln = tid & 63;
        last[l] = -1;
        __syncthreads();
        float x = x_ts[m * L_OBS + l];
        float t = t_ts[m * L_OBS + l];
        bool valid = (x == x) && (t >= 0.0f);
        int idx = (int)t;
        if (valid && idx < ALPHA) atomicMax(&last[idx], l);
        __syncthreads();
        int li = last[l];
        vals[l] = (li >= 0) ? x_ts[m * L_OBS + li] : 0.0f;
        int p = (li >= 0) ? l : -1;
        #pragma unroll
        for (int s = 1; s < 64; s <<= 1) {
            int q = __shfl_up(p, s);
            if (ln >= s && q > p) p = q;
        }
        if (ln == 63) wtot[wv] = p;
        __syncthreads();
        int pre = -1;
        for (int w = 0; w < 4; w++)
            if (w < wv && wtot[w] > pre) pre = wtot[w];
        int lp = (pre > p) ? pre : p;
        regular[m * ALPHA + l] = (lp >= 0) ? vals[lp] : gm[m];
    } else {
        // ---------------- weight fold + QW for 16 a ----------------
        const int pb = blockIdx.x - D_M;   // 0..127
        const int h  = pb >> 4;
        const int a0 = (pb & 15) * 16;

        {
            const float4* w4 = (const float4*)(wq_w + h * D_V * D_V);
            #pragma unroll
            for (int i = 0; i < 4; i++) {
                int f = i * 256 + tid;
                float4 v = w4[f];
                int e = f >> 4, c = (f & 15) * 4;
                *(float4*)&wq_s[e][c] = v;
            }
        }
        {
            int al = tid >> 4, j0 = (tid & 15) * 4;
            float tv = (float)(a0 + al);
            #pragma unroll
            for (int j = 0; j < 4; j++) {
                int d = j0 + j;
                float f = t2v_w[h * D_V + d] * tv + t2v_phi[h * D_V + d];
                thA[al][d] = (d == 0) ? f : __sinf(f);
            }
        }
        __syncthreads();

        // Phase A: QaT[a][e] = thA[a] . wq_s[e] + wq_b[e]
        {
            const int e  = tid >> 2;
            const int ap = tid & 3;
            float accA[4] = {0.f, 0.f, 0.f, 0.f};
            const float4* wrow = (const float4*)&wq_s[e][0];
            #pragma unroll
            for (int j = 0; j < 16; j++) {
                float4 w = wrow[j];
                #pragma unroll
                for (int k = 0; k < 4; k++) {
                    float4 tv = *(const float4*)&thA[ap + 4 * k][j * 4];
                    accA[k] += w.x * tv.x + w.y * tv.y + w.z * tv.z + w.w * tv.w;
                }
            }
            float bq = wq_b[h * D_V + e];
            #pragma unroll
            for (int k = 0; k < 4; k++) QaT[ap + 4 * k][e] = accA[k] + bq;
        }
        __syncthreads();

        // Phase B: QW[d][a] = sum_e QaT[a][e] * wk_w[h][e][d]
        const int d  = tid >> 2;
        const int ap = tid & 3;
        float accB[4] = {0.f, 0.f, 0.f, 0.f};
        #pragma unroll 4
        for (int e4 = 0; e4 < 16; e4++) {
            const float* wkp = &wk_w[(h * D_V + e4 * 4) * D_V + d];
            float w0 = wkp[0];
            float w1 = wkp[D_V];
            float w2 = wkp[2 * D_V];
            float w3 = wkp[3 * D_V];
            #pragma unroll
            for (int k = 0; k < 4; k++) {
                float4 qv = *(const float4*)&QaT[ap + 4 * k][e4 * 4];
                accB[k] += qv.x * w0 + qv.y * w1 + qv.z * w2 + qv.w * w3;
            }
        }
        #pragma unroll
        for (int k = 0; k < 4; k++)
            QWbuf[h * D_V * ALPHA + d * ALPHA + a0 + ap + 4 * k] = accB[k];

        // QWabs reduction: wq_s reused as red[d][a-local]
        __syncthreads();
        #pragma unroll
        for (int k = 0; k < 4; k++)
            wq_s[d][ap + 4 * k] = (d == 0) ? 0.0f : fabsf(accB[k]);
        __syncthreads();
        if (tid < 16) {
            float s = 0.0f;
            #pragma unroll 8
            for (int dd = 0; dd < D_V; dd++) s += wq_s[dd][tid];
            QWabsG[h * ALPHA + a0 + tid] = s;
        }
    }
}

// ---------------------------------------------------------------------------
// Kernel 2: mTAND attention via MFMA + compaction, 512 threads = 8 waves per
// (m,h) block covering ALL 256 a (wave w owns 2 a-tiles at w*32) -- halves
// chip-wide sin work vs the 2-half-block form (each (m,h) sin set computed
// once, shared by 8 waves). Grid (64,8) = 512 blocks.
// Compaction (ballot/popc by waves 0-3): loop runs nst = ceil(Lv/16) tiles;
// tail masked -1e9 -> exp2 = 0 (exact).
// 2 l-tiles per barrier region; 512 threads write BOTH tile slots per call
// (slot = tid>>8, 4 sins each) into the double-buffered frag LDS; writes
// issued before computes so sin VALU overlaps MFMA; one barrier per region.
// Bound-shifted softmax folded into MFMA C-init; d=0 exact in fp32; d>=1 via
// 3-term split-precision f16 MFMA (identical d-slot formula on A and B).
// ---------------------------------------------------------------------------
__global__ __launch_bounds__(512) void attn_mfma_kernel(
    const float* __restrict__ x_ts, const float* __restrict__ t_ts,
    const float* __restrict__ t2v_w, const float* __restrict__ t2v_phi,
    const float* __restrict__ QWbuf, const float* __restrict__ QWabsG,
    float* __restrict__ interp)
{
    const int m   = blockIdx.x;
    const int h   = blockIdx.y;
    const int tid = threadIdx.x;     // 0..511
    const int wv  = tid >> 6;        // wave 0..7
    const int ln  = tid & 63;
    const int lg  = ln >> 4;         // lane group (0..3)
    const int lc  = ln & 15;         // B col / A row within tile

    __shared__ float xc[L_OBS], tc[L_OBS];          // compacted obs
    __shared__ float w_sh[D_V], phi_sh[D_V];
    __shared__ __align__(16) _Float16 hiB[2][2048]; // 8 KiB (2 buf x 2 tiles)
    __shared__ __align__(16) _Float16 reB[2][2048]; // 8 KiB
    __shared__ float red_s[8];
    __shared__ int   cnt_s[4];

    // init pads + staging (obs handled by waves 0-3; tid == obs index)
    if (tid < L_OBS) { xc[tid] = 0.0f; tc[tid] = 0.0f; }
    if (tid < D_V)                      w_sh[tid]          = t2v_w[h * D_V + tid];
    else if (tid >= 256 && tid < 256 + D_V)
        phi_sh[tid - 256] = t2v_phi[h * D_V + tid - 256];

    float x = 0.0f, t = 0.0f;
    bool  v = false;
    unsigned long long bal = 0;
    if (tid < L_OBS) {
        x = x_ts[m * L_OBS + tid];
        t = t_ts[m * L_OBS + tid];
        v = (x == x) && (t >= 0.0f);
        bal = __ballot(v);
        if (ln == 0) cnt_s[wv] = __popcll(bal);
        float tmx = v ? t : -3.0e38f;
        float tmn = v ? t : 3.0e38f;
        #pragma unroll
        for (int s = 1; s < 64; s <<= 1) {
            tmx = fmaxf(tmx, __shfl_xor(tmx, s));
            tmn = fminf(tmn, __shfl_xor(tmn, s));
        }
        if (ln == 0) { red_s[wv] = tmx; red_s[4 + wv] = tmn; }
    }
    __syncthreads();   // pads + cnt_s + red_s + w/phi visible

    const int c0 = cnt_s[0], c1 = cnt_s[1], c2 = cnt_s[2], c3 = cnt_s[3];
    const int Lv = c0 + c1 + c2 + c3;
    if (tid < L_OBS && v) {
        int base = (wv > 0 ? c0 : 0) + (wv > 1 ? c1 : 0) + (wv > 2 ? c2 : 0);
        unsigned long long lm = (1ull << ln) - 1ull;
        int p = base + __popcll(bal & lm);
        xc[p] = x; tc[p] = t;
    }

    const float tmaxv = fmaxf(fmaxf(red_s[0], red_s[1]), fmaxf(red_s[2], red_s[3]));
    const float tminv = fminf(fminf(red_s[4], red_s[5]), fminf(red_s[6], red_s[7]));
    const bool  anyv  = tmaxv > -1.0e37f;

    const float* __restrict__ QWh = QWbuf + h * D_V * ALPHA;
    const float w0 = w_sh[0], p0 = phi_sh[0];
    const float SCALE2 = 0.18033688011112042f;   // 0.125 * log2(e)

    // ---- stage A fragments (hi + residual) + bound-folded C-init, 2 tiles ----
    half8 ahf[2][2], arf[2][2];
    float qw0[2][4], c0b[2][4];
    #pragma unroll
    for (int at = 0; at < 2; at++) {
        const int abase = wv * 32 + at * 16;
        const int arowA = abase + lc;
        #pragma unroll
        for (int kb = 0; kb < 2; kb++) {
            #pragma unroll
            for (int j = 0; j < 8; j++) {
                int d = 1 + kb * 32 + ((j >> 2) << 4) + (lg << 2) + (j & 3);
                float q = (d < D_V) ? QWh[d * ALPHA + arowA] : 0.0f;
                _Float16 qh = (_Float16)q;
                ahf[at][kb][j] = qh;
                arf[at][kb][j] = (_Float16)(q - (float)qh);
            }
        }
        const int arowD = abase + lg * 4;
        #pragma unroll
        for (int r = 0; r < 4; r++) {
            float q0 = QWh[arowD + r];
            qw0[at][r] = q0;
            float u = q0 * w0;
            float lin = q0 * p0 + fmaxf(u * tmaxv, u * tminv);
            c0b[at][r] = -(lin + QWabsG[h * ALPHA + arowD + r]);
        }
    }

    float ssum[2][4], axs[2][4];
    #pragma unroll
    for (int at = 0; at < 2; at++)
        #pragma unroll
        for (int r = 0; r < 4; r++) { ssum[at][r] = 0.0f; axs[at][r] = 0.0f; }

    // writer-role constants: 512 threads write 2 tiles per call (slot = tid>>8)
    const int slot = tid >> 8;                 // which tile of the region
    const int t2   = tid & 255;
    const int wc   = t2 >> 5;                  // combo = kb*4+lg, 0..7
    const int lcw  = (t2 >> 1) & 15;           // l within tile
    const int dB   = 1 + (wc >> 2) * 32 + (wc & 3) * 4 + ((t2 & 1) << 4);

    auto write2 = [&](int lt0, int buf) {      // writes tiles lt0, lt0+1
        int lt = lt0 + slot;
        float tvw = tc[lt * 16 + lcw];
        float s0 = __sinf(fmaf(w_sh[(dB + 0) & 63], tvw, phi_sh[(dB + 0) & 63]));
        float s1 = __sinf(fmaf(w_sh[(dB + 1) & 63], tvw, phi_sh[(dB + 1) & 63]));
        float s2 = __sinf(fmaf(w_sh[(dB + 2) & 63], tvw, phi_sh[(dB + 2) & 63]));
        float s3 = __sinf(fmaf(w_sh[(dB + 3) & 63], tvw, phi_sh[(dB + 3) & 63]));
        union { _Float16 hv[4]; float2 f2; } hw, rw;
        hw.hv[0] = (_Float16)s0; hw.hv[1] = (_Float16)s1;
        hw.hv[2] = (_Float16)s2; hw.hv[3] = (_Float16)s3;
        rw.hv[0] = (_Float16)(s0 - (float)hw.hv[0]);
        rw.hv[1] = (_Float16)(s1 - (float)hw.hv[1]);
        rw.hv[2] = (_Float16)(s2 - (float)hw.hv[2]);
        rw.hv[3] = (_Float16)(s3 - (float)hw.hv[3]);
        *(float2*)&hiB[buf][slot * 1024 + t2 * 4] = hw.f2;
        *(float2*)&reB[buf][slot * 1024 + t2 * 4] = rw.f2;
    };

    const int nst  = (Lv + 15) >> 4;     // tiles of 16 compacted l
    const int nreg = (nst + 1) >> 1;     // 2-tile barrier regions

    __syncthreads();   // scatter (xc/tc) visible before prologue sins
    write2(0, 0);
    __syncthreads();

    // ---- main loop: one barrier per 2-tile region ----
    for (int rg = 0; rg < nreg; rg++) {
        const int cur = rg & 1;
        // issue next region's sin-writes first (overlaps MFMA below)
        if (rg + 1 < nreg) write2(2 * rg + 2, cur ^ 1);
        #pragma unroll
        for (int s = 0; s < 2; s++) {
            const int st = 2 * rg + s;
            if (st >= nst) break;   // block-uniform (Lv shared)
            half8 bh[2], br[2];
            #pragma unroll
            for (int kb = 0; kb < 2; kb++) {
                int fi = s * 1024 + ((kb * 4 + lg) * 16 + lc) * 8;
                bh[kb] = *(const half8*)&hiB[cur][fi];
                br[kb] = *(const half8*)&reB[cur][fi];
            }
            const int l = st * 16 + lc;
            const float tv  = tc[l];
            const float xv  = xc[l];
            const float mkv = (l < Lv) ? 0.0f : -1.0e9f;
            const float tau = fmaf(w0, tv, p0);

            #pragma unroll
            for (int at = 0; at < 2; at++) {
                f32x4 acc;
                #pragma unroll
                for (int r = 0; r < 4; r++)
                    acc[r] = fmaf(qw0[at][r], tau, c0b[at][r]);  // exact d=0 - bound
                #pragma unroll
                for (int kb = 0; kb < 2; kb++) {
                    acc = __builtin_amdgcn_mfma_f32_16x16x32_f16(ahf[at][kb], bh[kb], acc, 0, 0, 0);
                    acc = __builtin_amdgcn_mfma_f32_16x16x32_f16(ahf[at][kb], br[kb], acc, 0, 0, 0);
                    acc = __builtin_amdgcn_mfma_f32_16x16x32_f16(arf[at][kb], bh[kb], acc, 0, 0, 0);
                }
                #pragma unroll
                for (int r = 0; r < 4; r++) {
                    float p = __builtin_amdgcn_exp2f(fmaf(acc[r], SCALE2, mkv));
                    ssum[at][r] += p;
                    axs[at][r]   = fmaf(p, xv, axs[at][r]);
                }
            }
        }
        __syncthreads();
    }

    // ---- merge across the 16 lc lanes, write interp [a][m][h] ----
    #pragma unroll
    for (int at = 0; at < 2; at++) {
        #pragma unroll
        for (int r = 0; r < 4; r++) {
            float S = ssum[at][r];
            float A = axs[at][r];
            S += __shfl_xor(S, 1); A += __shfl_xor(A, 1);
            S += __shfl_xor(S, 2); A += __shfl_xor(A, 2);
            S += __shfl_xor(S, 4); A += __shfl_xor(A, 4);
            S += __shfl_xor(S, 8); A += __shfl_xor(A, 8);
            if (lc == 0) {
                int a = wv * 32 + at * 16 + lg * 4 + r;
                interp[a * (D_M * N_HEADS) + m * N_HEADS + h] =
                    anyv ? (A / S) : 0.0f;
            }
        }
    }
}

// ---------------------------------------------------------------------------
// Kernel 3: fused e_imp + e_attn + gate MLP + output. Block per a, 256 thr.
// ---------------------------------------------------------------------------
__global__ __launch_bounds__(256) void final_kernel(
    const float* __restrict__ regular, const float* __restrict__ interp,
    const float* __restrict__ conv_w, const float* __restrict__ conv_b,
    const float* __restrict__ proj_w, const float* __restrict__ proj_b,
    const float* __restrict__ g1_w, const float* __restrict__ g1_b,
    const float* __restrict__ g2_w, const float* __restrict__ g2_b,
    float* __restrict__ out)
{
    const int a = blockIdx.x;
    const int tid = threadIdx.x;
    __shared__ float isum_s[N_HEADS];
    __shared__ __align__(16) float col[D_M];
    __shared__ __align__(16) float c_s[2 * D_H];
    __shared__ __align__(16) float h_s[D_H];

    if (tid < 64) {
        const float4* i4 = (const float4*)&interp[a * (D_M * N_HEADS) + tid * 8];
        float4 v0 = i4[0], v1 = i4[1];
        float v[8] = {v0.x, v0.y, v0.z, v0.w, v1.x, v1.y, v1.z, v1.w};
        #pragma unroll
        for (int s = 1; s < 64; s <<= 1) {
            #pragma unroll
            for (int j = 0; j < 8; j++) v[j] += __shfl_xor(v[j], s);
        }
        if (tid == 0) {
            #pragma unroll
            for (int j = 0; j < 8; j++) isum_s[j] = v[j];
        }
    } else if (tid < 128) {
        col[tid - 64] = regular[(tid - 64) * ALPHA + a];
    }
    __syncthreads();

    float vattn;
    {
        const float4* p4 = (const float4*)&proj_w[tid * N_HEADS];
        float4 v0 = p4[0], v1 = p4[1];
        float sum = v0.x * isum_s[0] + v0.y * isum_s[1] + v0.z * isum_s[2]
                  + v0.w * isum_s[3] + v1.x * isum_s[4] + v1.y * isum_s[5]
                  + v1.z * isum_s[6] + v1.w * isum_s[7];
        vattn = proj_b[tid] + sum * (1.0f / 64.0f);
    }
    float vimp;
    {
        const float4* row = (const float4*)&conv_w[tid * D_M];
        const float4* c4  = (const float4*)col;
        float s0 = 0.f, s1 = 0.f, s2 = 0.f, s3 = 0.f;
        #pragma unroll
        for (int i = 0; i < D_M / 4; i++) {
            float4 r = row[i]; float4 c = c4[i];
            s0 += r.x * c.x; s1 += r.y * c.y; s2 += r.z * c.z; s3 += r.w * c.w;
        }
        vimp = conv_b[tid] + ((s0 + s1) + (s2 + s3));
    }
    c_s[tid]       = vimp;
    c_s[D_H + tid] = vattn;
    __syncthreads();

    {
        const float4* grow = (const float4*)&g1_w[tid * 2 * D_H];
        const float4* c4 = (const float4*)c_s;
        float s0 = 0.f, s1 = 0.f, s2 = 0.f, s3 = 0.f;
        #pragma unroll 8
        for (int i = 0; i < (2 * D_H) / 4; i++) {
            float4 g = grow[i]; float4 c = c4[i];
            s0 += g.x * c.x; s1 += g.y * c.y; s2 += g.z * c.z; s3 += g.w * c.w;
        }
        float hid = g1_b[tid] + ((s0 + s1) + (s2 + s3));
        h_s[tid] = fmaxf(hid, 0.0f);
    }
    __syncthreads();
    {
        const float4* grow = (const float4*)&g2_w[tid * D_H];
        const float4* h4 = (const float4*)h_s;
        float s0 = 0.f, s1 = 0.f, s2 = 0.f, s3 = 0.f;
        #pragma unroll 8
        for (int i = 0; i < D_H / 4; i++) {
            float4 g = grow[i]; float4 hh = h4[i];
            s0 += g.x * hh.x; s1 += g.y * hh.y; s2 += g.z * hh.z; s3 += g.w * hh.w;
        }
        float z = g2_b[tid] + ((s0 + s1) + (s2 + s3));
        float gate = 1.0f / (1.0f + __expf(-z));
        out[a * D_H + tid] = gate * vimp + (1.0f - gate) * vattn;
    }
}

// ---------------------------------------------------------------------------
extern "C" void kernel_launch(void* const* d_in, const int* in_sizes, int n_in,
                              void* d_out, int out_size, void* d_ws, size_t ws_size,
                              hipStream_t stream)
{
    (void)in_sizes; (void)n_in; (void)out_size; (void)ws_size;

    const float* x_ts    = (const float*)d_in[0];
    const float* t_ts    = (const float*)d_in[1];
    const float* gm      = (const float*)d_in[2];
    const float* conv_w  = (const float*)d_in[3];
    const float* conv_b  = (const float*)d_in[4];
    const float* t2v_w   = (const float*)d_in[5];
    const float* t2v_phi = (const float*)d_in[6];
    const float* wq_w    = (const float*)d_in[7];
    const float* wq_b    = (const float*)d_in[8];
    const float* wk_w    = (const float*)d_in[9];
    const float* proj_w  = (const float*)d_in[11];
    const float* proj_b  = (const float*)d_in[12];
    const float* g1_w    = (const float*)d_in[13];
    const float* g1_b    = (const float*)d_in[14];
    const float* g2_w    = (const float*)d_in[15];
    const float* g2_b    = (const float*)d_in[16];

    float* out = (float*)d_out;

    float* ws      = (float*)d_ws;
    float* regular = ws;                               // 16384
    float* QWbuf   = regular + D_M * ALPHA;            // 131072  [h][d][a]
    float* interp  = QWbuf + N_HEADS * D_V * ALPHA;    // 131072  [a][m][h]
    float* QWabs   = interp + ALPHA * D_M * N_HEADS;   // 2048    [h][a]

    prep_kernel<<<D_M + 128, 256, 0, stream>>>(
        x_ts, t_ts, gm, t2v_w, t2v_phi, wq_w, wq_b, wk_w,
        regular, QWbuf, QWabs);
    attn_mfma_kernel<<<dim3(D_M, N_HEADS), 512, 0, stream>>>(
        x_ts, t_ts, t2v_w, t2v_phi, QWbuf, QWabs, interp);
    final_kernel<<<ALPHA, 256, 0, stream>>>(
        regular, interp, conv_w, conv_b, proj_w, proj_b,
        g1_w, g1_b, g2_w, g2_b, out);
}